// Round 9
// baseline (25.449 us; speedup 1.0000x reference)
//
#include <hip/hip_runtime.h>

// Bidirectional Chamfer distance, fp32, shapes (16, 2048, 3).
//
// R9: Q=16 queries/lane + quarter-target blocks -> LDS reads/CU drop to 512
// (below the VALU floor); inner loop stays packed fp32 (v_pk_fma_f32).
// VGPR pressure handled with VOP3P op_sel: each f2 register holds TWO
// DIFFERENT queries' components; two pk_fma asm variants broadcast either
// the lo half (query 2i) or hi half (query 2i+1) to both packed lanes.
//
//  - chamfer: 256 blocks = qset(64: dir x batch x qchunk) x quarter(4),
//    1024 thr = 16 waves. Block owns 1024 queries (Q=16/lane) and scans its
//    512-target quarter from LDS (pairwise f4: {x0,x1,y0,y1}/{z0,z1,w0,w1}).
//    Wave scans 16 pairs -> 32 ds_read_b128; per pair per query:
//    3 pk_fma + 1 v_min3 (2 instr/visit). Output: 1024 per-query mins.
//  - reduce1: 64 blocks (one per qset): min over 4 quarters, sum over 1024
//    queries -> gsum[64].
//  - reduce2: 1 wave: sum gsum -> out[0] / 32768.
// No atomics, no memset; all consumed ws bytes rewritten every call.
//
// Math: d2 = |p|^2 + |t|^2 - 2 p.t; q=-2p folded; |p|^2 added at smin-write.

typedef float f2 __attribute__((ext_vector_type(2)));
typedef float f4 __attribute__((ext_vector_type(4)));

#define NPTS  2048
#define BATCH 16
#define NBLK  256
#define QPB   1024           // queries per block
#define TPB   512            // targets per block (quarter cloud)
#define NQS   64             // query sets

// Both packed half-ops read src0.lo (query 2i):
static __device__ __forceinline__ f2 pk_fma_lo(f2 a, f2 b, f2 c) {
    f2 d;
    asm("v_pk_fma_f32 %0, %1, %2, %3 op_sel:[0,0,0] op_sel_hi:[0,1,1]"
        : "=v"(d) : "v"(a), "v"(b), "v"(c));
    return d;
}
// Both packed half-ops read src0.hi (query 2i+1):
static __device__ __forceinline__ f2 pk_fma_hi(f2 a, f2 b, f2 c) {
    f2 d;
    asm("v_pk_fma_f32 %0, %1, %2, %3 op_sel:[1,0,0] op_sel_hi:[1,1,1]"
        : "=v"(d) : "v"(a), "v"(b), "v"(c));
    return d;
}

__global__ __launch_bounds__(1024) void chamfer_kernel(
    const float* __restrict__ pred,
    const float* __restrict__ tgt,
    float* __restrict__ partial)     // [NBLK][QPB]
{
    const int bid = blockIdx.x;
    const int qs  = bid >> 2;          // query set 0..63
    const int qt  = bid & 3;           // target quarter
    const int dir = qs >> 5;           // 0: pred->tgt, 1: tgt->pred
    const int b   = (qs >> 1) & 15;    // batch
    const int qc  = qs & 1;            // query chunk of 1024

    const int tid  = threadIdx.x;
    const int lane = tid & 63;
    const int w    = tid >> 6;         // wave 0..15

    const float* __restrict__ P = dir ? tgt  : pred;  // query cloud
    const float* __restrict__ T = dir ? pred : tgt;   // other cloud
    const float* Pb = P + (size_t)b * NPTS * 3;
    const float* Tb = T + (size_t)b * NPTS * 3 + (size_t)qt * TPB * 3;

    __shared__ f4    t2a[TPB / 2];     // 4 KB: {x0,x1,y0,y1} per pair
    __shared__ f4    t2b[TPB / 2];     // 4 KB: {z0,z1,w0,w1} per pair
    __shared__ float smin[16][QPB];    // 64 KB: per-wave partial mins

    // --- Stage 256 target-pairs into LDS ---
    if (tid < TPB / 2) {
        const int jp = tid;
        const float x0 = Tb[(2 * jp) * 3 + 0];
        const float y0 = Tb[(2 * jp) * 3 + 1];
        const float z0 = Tb[(2 * jp) * 3 + 2];
        const float x1 = Tb[(2 * jp + 1) * 3 + 0];
        const float y1 = Tb[(2 * jp + 1) * 3 + 1];
        const float z1 = Tb[(2 * jp + 1) * 3 + 2];
        f4 A; A.x = x0; A.y = x1; A.z = y0; A.w = y1;
        f4 B; B.x = z0; B.y = z1;
        B.z = x0 * x0 + y0 * y0 + z0 * z0;
        B.w = x1 * x1 + y1 * y1 + z1 * z1;
        t2a[jp] = A;
        t2b[jp] = B;
    }

    // --- 16 queries/lane; fold -2; two queries per f2 register ---
    f2 qx2[8], qy2[8], qz2[8], pp2[8];
    float m[16];
    #pragma unroll
    for (int i = 0; i < 8; ++i) {
        #pragma unroll
        for (int h = 0; h < 2; ++h) {
            const int qi = qc * QPB + (2 * i + h) * 64 + lane;
            const float x = Pb[qi * 3 + 0];
            const float y = Pb[qi * 3 + 1];
            const float z = Pb[qi * 3 + 2];
            qx2[i][h] = -2.0f * x;
            qy2[i][h] = -2.0f * y;
            qz2[i][h] = -2.0f * z;
            pp2[i][h] = x * x + y * y + z * z;
            m[2 * i + h] = 3.4e38f;
        }
    }

    __syncthreads();

    // --- Scan this wave's 16 target-pairs (32 targets) ---
    const int pbase = w * 16;
    #pragma unroll 2
    for (int jp = 0; jp < 16; jp += 2) {
        const f4 A0 = t2a[pbase + jp + 0];
        const f4 B0 = t2b[pbase + jp + 0];
        const f4 A1 = t2a[pbase + jp + 1];
        const f4 B1 = t2b[pbase + jp + 1];
        #pragma unroll
        for (int i = 0; i < 8; ++i) {
            // query 2i vs pair 0
            f2 s0 = pk_fma_lo(qx2[i], A0.lo, B0.hi);
            s0 = pk_fma_lo(qy2[i], A0.hi, s0);
            s0 = pk_fma_lo(qz2[i], B0.lo, s0);
            m[2 * i] = fminf(fminf(m[2 * i], s0.x), s0.y);        // v_min3
            // query 2i+1 vs pair 0
            f2 s1 = pk_fma_hi(qx2[i], A0.lo, B0.hi);
            s1 = pk_fma_hi(qy2[i], A0.hi, s1);
            s1 = pk_fma_hi(qz2[i], B0.lo, s1);
            m[2 * i + 1] = fminf(fminf(m[2 * i + 1], s1.x), s1.y);
            // query 2i vs pair 1
            f2 s2 = pk_fma_lo(qx2[i], A1.lo, B1.hi);
            s2 = pk_fma_lo(qy2[i], A1.hi, s2);
            s2 = pk_fma_lo(qz2[i], B1.lo, s2);
            m[2 * i] = fminf(fminf(m[2 * i], s2.x), s2.y);
            // query 2i+1 vs pair 1
            f2 s3 = pk_fma_hi(qx2[i], A1.lo, B1.hi);
            s3 = pk_fma_hi(qy2[i], A1.hi, s3);
            s3 = pk_fma_hi(qz2[i], B1.lo, s3);
            m[2 * i + 1] = fminf(fminf(m[2 * i + 1], s3.x), s3.y);
        }
    }

    // --- Cross-wave min combine (add |p|^2 here: commutes with min) ---
    #pragma unroll
    for (int i = 0; i < 8; ++i) {
        smin[w][(2 * i + 0) * 64 + lane] = m[2 * i + 0] + pp2[i][0];
        smin[w][(2 * i + 1) * 64 + lane] = m[2 * i + 1] + pp2[i][1];
    }
    __syncthreads();

    // --- Per-query min over 16 waves; contiguous 1024-float store ---
    {
        float v = smin[0][tid];
        #pragma unroll
        for (int ww = 1; ww < 16; ++ww)
            v = fminf(v, smin[ww][tid]);
        partial[(size_t)bid * QPB + tid] = v;   // true d2 >= 0
    }
}

// reduce1: one block per query set: componentwise min over the 4 target
// quarters, sum over 1024 queries -> gsum[qs]. 256 thr, one float4 each.
__global__ __launch_bounds__(256) void reduce1_kernel(
    const float* __restrict__ partial,
    float* __restrict__ gsum)
{
    const int qs   = blockIdx.x;
    const int tid  = threadIdx.x;
    const int lane = tid & 63;
    const int w    = tid >> 6;
    __shared__ float s[4];

    const float4* P4 = (const float4*)(partial + (size_t)qs * 4 * QPB);
    const float4 v0 = P4[0 * (QPB / 4) + tid];
    const float4 v1 = P4[1 * (QPB / 4) + tid];
    const float4 v2 = P4[2 * (QPB / 4) + tid];
    const float4 v3 = P4[3 * (QPB / 4) + tid];

    const float mx = fminf(fminf(v0.x, v1.x), fminf(v2.x, v3.x));
    const float my = fminf(fminf(v0.y, v1.y), fminf(v2.y, v3.y));
    const float mz = fminf(fminf(v0.z, v1.z), fminf(v2.z, v3.z));
    const float mw = fminf(fminf(v0.w, v1.w), fminf(v2.w, v3.w));
    float acc = (mx + my) + (mz + mw);

    #pragma unroll
    for (int off = 32; off > 0; off >>= 1)
        acc += __shfl_down(acc, off);
    if (lane == 0) s[w] = acc;
    __syncthreads();
    if (tid == 0)
        gsum[qs] = (s[0] + s[1]) + (s[2] + s[3]);
}

// reduce2: one wave sums the 64 query-set sums -> out[0].
__global__ __launch_bounds__(64) void reduce2_kernel(
    const float* __restrict__ gsum,
    float* __restrict__ out)
{
    float v = gsum[threadIdx.x];
    #pragma unroll
    for (int off = 32; off > 0; off >>= 1)
        v += __shfl_down(v, off);
    if (threadIdx.x == 0)
        out[0] = v * (1.0f / (float)(BATCH * NPTS));
}

extern "C" void kernel_launch(void* const* d_in, const int* in_sizes, int n_in,
                              void* d_out, int out_size, void* d_ws, size_t ws_size,
                              hipStream_t stream)
{
    const float* pred = (const float*)d_in[0];
    const float* tgt  = (const float*)d_in[1];
    float* out = (float*)d_out;
    float* partial = (float*)d_ws;                            // 1 MB
    float* gsum    = (float*)d_ws + (size_t)NBLK * QPB;       // 64 floats

    chamfer_kernel<<<dim3(NBLK), dim3(1024), 0, stream>>>(pred, tgt, partial);
    reduce1_kernel<<<dim3(NQS), dim3(256), 0, stream>>>(partial, gsum);
    reduce2_kernel<<<dim3(1), dim3(64), 0, stream>>>(gsum, out);
}

// Round 10
// 19.750 us; speedup vs baseline: 1.2886x; 1.2886x over previous
//
#include <hip/hip_runtime.h>

// Bidirectional Chamfer distance, fp32, shapes (16, 2048, 3).
//
// R10 = R8's chamfer (known-good) + 2-node graph:
//  - chamfer: 256 blocks = dir(2) x batch(16) x qchunk(4) x target-half(2),
//    1024 thr = 16 waves. Block owns 512 queries (Q=8/lane, packed fp32:
//    v_pk_fma_f32 over target PAIRS) and scans its 1024-target half from
//    LDS (pairwise f4 {x0,x1,y0,y1}/{z0,z1,w0,w1} -> 1 ds_read_b128 per
//    target visit per wave). Per pair per query: 3 pk_fma + 1 v_min3.
//    Output: 512 per-query mins -> d_ws. Thread (0,0) also zeroes out[0]
//    (only read by node 2; stream order makes this safe, replaces memset).
//  - reduce: 128 blocks, one per (dir,b,qc) group: min over the two
//    target-half blocks, sum over 512 queries, one scaled atomicAdd into
//    out[0] (128 device-scope relaxed atomics total, ~1 us).
//
// Math: d2 = |p|^2 + |t|^2 - 2 p.t; q=-2p folded; |p|^2 added at smin-write.

typedef float f2 __attribute__((ext_vector_type(2)));
typedef float f4 __attribute__((ext_vector_type(4)));

#define NPTS  2048
#define BATCH 16
#define NBLK  256
#define QPB   512            // queries per block
#define TPB   1024           // targets per block (half cloud)
#define NGRP  128            // (dir, batch, qchunk) groups

static __device__ __forceinline__ f2 pk_fma(f2 a, f2 b, f2 c) {
    f2 d;
    asm("v_pk_fma_f32 %0, %1, %2, %3" : "=v"(d) : "v"(a), "v"(b), "v"(c));
    return d;
}

__global__ __launch_bounds__(1024) void chamfer_kernel(
    const float* __restrict__ pred,
    const float* __restrict__ tgt,
    float* __restrict__ partial,     // [NBLK][QPB]
    float* __restrict__ out)
{
    const int bid = blockIdx.x;
    const int dir = bid >> 7;          // 0: pred->tgt, 1: tgt->pred
    const int b   = (bid >> 3) & 15;   // batch
    const int qc  = (bid >> 1) & 3;    // query chunk of 512
    const int th  = bid & 1;           // target half

    const int tid  = threadIdx.x;
    const int lane = tid & 63;
    const int w    = tid >> 6;         // wave 0..15

    // out[0] is only read by the reduce dispatch; stream order makes this
    // a safe replacement for a hipMemsetAsync node.
    if (bid == 0 && tid == 0) out[0] = 0.0f;

    const float* __restrict__ P = dir ? tgt  : pred;  // query cloud
    const float* __restrict__ T = dir ? pred : tgt;   // other cloud
    const float* Pb = P + (size_t)b * NPTS * 3;
    const float* Tb = T + (size_t)b * NPTS * 3 + (size_t)th * TPB * 3;

    __shared__ f4    t2a[TPB / 2];     // 8 KB: {x0,x1,y0,y1} per pair
    __shared__ f4    t2b[TPB / 2];     // 8 KB: {z0,z1,w0,w1} per pair
    __shared__ float smin[16][QPB];    // 32 KB: per-wave partial mins

    // --- Stage 512 target-pairs into LDS (one pair per thread < 512) ---
    if (tid < TPB / 2) {
        const int jp = tid;
        const float x0 = Tb[(2 * jp) * 3 + 0];
        const float y0 = Tb[(2 * jp) * 3 + 1];
        const float z0 = Tb[(2 * jp) * 3 + 2];
        const float x1 = Tb[(2 * jp + 1) * 3 + 0];
        const float y1 = Tb[(2 * jp + 1) * 3 + 1];
        const float z1 = Tb[(2 * jp + 1) * 3 + 2];
        f4 A; A.x = x0; A.y = x1; A.z = y0; A.w = y1;
        f4 B; B.x = z0; B.y = z1;
        B.z = x0 * x0 + y0 * y0 + z0 * z0;
        B.w = x1 * x1 + y1 * y1 + z1 * z1;
        t2a[jp] = A;
        t2b[jp] = B;
    }

    // --- Load 8 queries/lane; fold -2; replicate into packed halves ---
    f2 qx2[8], qy2[8], qz2[8];
    float pp[8], m0[8], m1[8];
    #pragma unroll
    for (int q = 0; q < 8; ++q) {
        const int qi = qc * QPB + q * 64 + lane;
        const float x = Pb[qi * 3 + 0];
        const float y = Pb[qi * 3 + 1];
        const float z = Pb[qi * 3 + 2];
        const float ax = -2.0f * x, ay = -2.0f * y, az = -2.0f * z;
        qx2[q].x = ax; qx2[q].y = ax;
        qy2[q].x = ay; qy2[q].y = ay;
        qz2[q].x = az; qz2[q].y = az;
        pp[q] = x * x + y * y + z * z;
        m0[q] = 3.4e38f;
        m1[q] = 3.4e38f;
    }

    __syncthreads();

    // --- Scan this wave's 32 target-pairs (64 targets) ---
    const int base = w * 32;
    #pragma unroll 4
    for (int jp = 0; jp < 32; jp += 2) {
        const f4 A0 = t2a[base + jp + 0];
        const f4 B0 = t2b[base + jp + 0];
        const f4 A1 = t2a[base + jp + 1];
        const f4 B1 = t2b[base + jp + 1];
        #pragma unroll
        for (int q = 0; q < 8; ++q) {
            f2 s0 = pk_fma(qx2[q], A0.lo, B0.hi);   // x*qx + |t|^2
            s0 = pk_fma(qy2[q], A0.hi, s0);
            s0 = pk_fma(qz2[q], B0.lo, s0);
            m0[q] = fminf(fminf(m0[q], s0.x), s0.y);   // v_min3_f32
            f2 s1 = pk_fma(qx2[q], A1.lo, B1.hi);
            s1 = pk_fma(qy2[q], A1.hi, s1);
            s1 = pk_fma(qz2[q], B1.lo, s1);
            m1[q] = fminf(fminf(m1[q], s1.x), s1.y);   // v_min3_f32
        }
    }

    // --- Cross-wave min combine (add |p|^2 here: commutes with min) ---
    #pragma unroll
    for (int q = 0; q < 8; ++q)
        smin[w][q * 64 + lane] = fminf(m0[q], m1[q]) + pp[q];
    __syncthreads();

    // --- Per-query min over 16 waves; contiguous 512-float store ---
    if (tid < QPB) {
        float v = smin[0][tid];
        #pragma unroll
        for (int ww = 1; ww < 16; ++ww)
            v = fminf(v, smin[ww][tid]);
        partial[(size_t)bid * QPB + tid] = v;   // true d2 >= 0
    }
}

// reduce: one block per (dir,b,qc) group. 128 threads = 2 waves; each
// thread handles one float4 (4 queries): min over the two target-half
// blocks, then block sum, then ONE scaled atomicAdd into out[0].
__global__ __launch_bounds__(128) void reduce_kernel(
    const float* __restrict__ partial,
    float* __restrict__ out)
{
    const int g    = blockIdx.x;       // 0..127
    const int tid  = threadIdx.x;      // 0..127
    const int lane = tid & 63;
    const int w    = tid >> 6;
    __shared__ float s[2];

    const float4* p0 = (const float4*)(partial + (size_t)(2 * g)     * QPB);
    const float4* p1 = (const float4*)(partial + (size_t)(2 * g + 1) * QPB);
    const float4 a = p0[tid];          // 128 float4 = 512 queries (half 0)
    const float4 c = p1[tid];          // half 1

    float acc = fminf(a.x, c.x) + fminf(a.y, c.y)
              + fminf(a.z, c.z) + fminf(a.w, c.w);

    #pragma unroll
    for (int off = 32; off > 0; off >>= 1)
        acc += __shfl_down(acc, off);
    if (lane == 0) s[w] = acc;
    __syncthreads();

    if (tid == 0)
        atomicAdd(out, (s[0] + s[1]) * (1.0f / (float)(BATCH * NPTS)));
}

extern "C" void kernel_launch(void* const* d_in, const int* in_sizes, int n_in,
                              void* d_out, int out_size, void* d_ws, size_t ws_size,
                              hipStream_t stream)
{
    const float* pred = (const float*)d_in[0];
    const float* tgt  = (const float*)d_in[1];
    float* out = (float*)d_out;
    float* partial = (float*)d_ws;     // 256 * 512 floats = 512 KB, fully
                                       // rewritten each call

    chamfer_kernel<<<dim3(NBLK), dim3(1024), 0, stream>>>(pred, tgt, partial, out);
    reduce_kernel<<<dim3(NGRP), dim3(128), 0, stream>>>(partial, out);
}